// Round 1
// 127.609 us; speedup vs baseline: 1.0011x; 1.0011x over previous
//
#include <hip/hip_runtime.h>
#include <math.h>

// Problem constants
constexpr int Bn = 32;
constexpr int Cn = 512;
constexpr int Tn = 1024;
constexpr int KS = 13;

// Tiling
constexpr int CB   = 32;           // channels per block (halved vs r8: 512 blocks -> 2 blocks/CU)
constexpr int TT   = 64;           // timesteps per chunk
constexpr int NCH  = Tn / TT;      // 16 chunks
constexpr int DSTR = TT + 1;       // 65: odd -> conflict-free scan column reads
constexpr int NCW  = 4;            // conv waves
constexpr int SEG  = CB / NCW;     // 8 output rows per conv thread
constexpr int NL   = SEG + KS - 1; // 20 input rows per conv thread

// ---------------------------------------------------------------------------
// r9: latency-bound diagnosis (Occ 10.6%, VALU 27%, HBM 28%, 7000 cyc/chunk
// vs ~1500 cyc of stage work). Two fixes:
//  (1) 2 pipelines/CU: CB 64->32 => grid 512 blocks; LDS 17.2 KB/block and
//      __launch_bounds__(384,3) so two blocks co-reside and fill each
//      other's serialization bubbles.
//  (2) spin ring (LDS atomics, 4-slot) -> barrier double buffer: ONE raw
//      s_barrier per chunk. NOT __syncthreads: its vmcnt(0) drain would
//      defeat the distance-2 register prefetch and stall fire-and-forget
//      stores. Producers drain lgkmcnt only.
// Iteration k (uniform across roles, 17 barriers each):
//   conv waves : issue loads chunk k+3 (3-buffer rotation), conv chunk k+1
//                -> D[(k+1)&1], lgkmcnt(0), barrier
//   scan wave  : scan chunk k from D[k&1] -> Sb[k&1], lgkmcnt(0), barrier
//   store wave : store chunk k-1 from Sb[(k-1)&1] (fire & forget), barrier
// Math (kw double-exp emulation, ascending no-FMA conv, SCAN16, store) is
// bit-identical to the validated r2..r8 kernels.
// ---------------------------------------------------------------------------

__device__ __forceinline__ void wg_barrier() {
  asm volatile("" ::: "memory");
  __builtin_amdgcn_s_barrier();
  asm volatile("" ::: "memory");
}
__device__ __forceinline__ void lds_fence() {
  asm volatile("s_waitcnt lgkmcnt(0)" ::: "memory");
}

#define SCAN16(DV, TB)                                                   \
  _Pragma("unroll")                                                      \
  for (int j = 0; j < 16; ++j) {                                         \
    const float rthr = (mem > 0.5f) ? 0.5f : 0.0f;  /* reset: OLD mem */ \
    float a_  = __fmul_rn(0.95f, mem);                                   \
    float s2_ = __fadd_rn(a_, DV[j]);                                    \
    mem = __fsub_rn(s2_, rthr);                                          \
    const unsigned int bit = (mem > 0.5f) ? 1u : 0u;                     \
    if ((TB) + j < 32) lo |= bit << ((TB) + j);                          \
    else               hi |= bit << ((TB) + j - 32);                     \
  }

__global__ __launch_bounds__(384, 3)
void snn_fused(const float* __restrict__ x, const float* __restrict__ wp,
               float* __restrict__ out) {
  __shared__ float D[2][CB][DSTR];           // drive double buffer (16.6 KB)
  __shared__ unsigned long long Sb[2][CB];   // spike bitmask double buffer

  const int tid = threadIdx.x;
  const int b   = blockIdx.y;
  const int c0  = blockIdx.x * CB;
  const long xbase = (long)b * Cn * Tn;

  // ---- Gaussian weights, numpy float32 bit-emulation (validated) ----
  float kw[KS];
  {
    float w  = wp[0];
    float wc = fminf(fmaxf(w, 1.0f), 10.0f);      // clip(w, 1, 10)
    float sigma = __fadd_rn(5.5f, wc);
    float e[KS];
#pragma unroll
    for (int i = 0; i < KS; ++i) {
      float q = __fdiv_rn((float)(i - 6), sigma);
      float t = __fmul_rn(-0.5f, __fmul_rn(q, q));
      e[i] = (float)exp((double)t);
    }
    // numpy pairwise_sum order for n=13
    float s = __fadd_rn(
        __fadd_rn(__fadd_rn(e[0], e[1]), __fadd_rn(e[2], e[3])),
        __fadd_rn(__fadd_rn(e[4], e[5]), __fadd_rn(e[6], e[7])));
    s = __fadd_rn(s, e[8]);  s = __fadd_rn(s, e[9]);  s = __fadd_rn(s, e[10]);
    s = __fadd_rn(s, e[11]); s = __fadd_rn(s, e[12]);
#pragma unroll
    for (int i = 0; i < KS; ++i) kw[i] = __fdiv_rn(e[i], s);
  }

  if (tid < 64) {
    // ======================= scan wave (lanes >= CB masked) =============
    const int c = tid;
    float mem = 0.0f;
    wg_barrier();                              // prologue: conv(0) -> D[0]
    for (int k = 0; k < NCH; ++k) {
      if (c < CB) {
        const float* Dc = &D[k & 1][c][0];     // stride-65 row: conflict-free
        unsigned int lo = 0u, hi = 0u;
        float dvA[16], dvB[16];                // named arrays, const idx only
#pragma unroll
        for (int j = 0; j < 16; ++j) dvA[j] = Dc[j];
#pragma unroll
        for (int j = 0; j < 16; ++j) dvB[j] = Dc[16 + j];   // lookahead g=1
        SCAN16(dvA, 0)
#pragma unroll
        for (int j = 0; j < 16; ++j) dvA[j] = Dc[32 + j];   // lookahead g=2
        SCAN16(dvB, 16)
#pragma unroll
        for (int j = 0; j < 16; ++j) dvB[j] = Dc[48 + j];   // lookahead g=3
        SCAN16(dvA, 32)
        SCAN16(dvB, 48)
        Sb[k & 1][c] = ((unsigned long long)hi << 32) | (unsigned long long)lo;
      }
      lds_fence();                             // Sb/D reads retired pre-barrier
      wg_barrier();
    }
  } else if (tid < 64 + 64 * NCW) {
    // ============== conv waves (loads + conv + LDS writes) ==============
    const int ctid = tid - 64;
    const int col  = ctid & 63;               // t-column (lane)
    const int segS = (ctid >> 6) * SEG;       // 0,8,16,24
    const int cin0 = c0 + segS - 6;

    float xA[NL], xB[NL], xC[NL];             // 3-buffer rotation (named)

    auto load_chunk = [&](int m, float* dst) {
#pragma unroll
      for (int j = 0; j < NL; ++j) {
        const int gc = cin0 + j;
        float v = 0.0f;
        if (gc >= 0 && gc < Cn)               // zero pad; per-wave uniform
          v = x[xbase + (long)gc * Tn + m * TT + col];
        dst[j] = v;
      }
    };
    auto conv_chunk = [&](const float* xs, int p) {
#pragma unroll
      for (int r = 0; r < SEG; ++r) {
        float acc = __fmul_rn(kw[0], xs[r]);  // ascending, no FMA
#pragma unroll
        for (int i = 1; i < KS; ++i)
          acc = __fadd_rn(acc, __fmul_rn(kw[i], xs[r + i]));
        D[p][segS + r][col] = __fsub_rn(xs[r + 6], acc);  // x - x_mean
      }
    };

    load_chunk(0, xA);
    load_chunk(1, xB);
    load_chunk(2, xC);
    conv_chunk(xA, 0);                         // chunk 0 -> D[0] (waits xA only)
    lds_fence();
    wg_barrier();

    // Iter K (0..14): issue loads K+3 (distance-2 from consumption), conv
    // chunk K+1 from the buffer loaded two iterations ago, lgkm, barrier.
#define STEP(K, BL, BC)                                                  \
    do {                                                                 \
      if ((K) + 3 < NCH) load_chunk((K) + 3, BL);                        \
      conv_chunk(BC, ((K) + 1) & 1);                                     \
      lds_fence();                                                       \
      wg_barrier();                                                      \
    } while (0)

    for (int kb = 0; kb < NCH - 1; kb += 3) {  // kb=0,3,6,9,12 -> K=0..14
      STEP(kb + 0, xA, xB);
      STEP(kb + 1, xB, xC);
      STEP(kb + 2, xC, xA);
    }
#undef STEP
    wg_barrier();                              // iter 15: no conv work
  } else {
    // ====== store wave (LDS reads + global stores, NEVER waits vmcnt) ===
    const int col = tid & 63;                  // t-column (lane)
    wg_barrier();                              // prologue
    for (int k = 0; k < NCH; ++k) {
      if (k > 0) {
        const int km  = k - 1;
        const int t0p = km * TT;
#pragma unroll 8
        for (int r = 0; r < CB; ++r) {
          const unsigned long long wb = Sb[km & 1][r];     // LDS broadcast
          const float v = ((wb >> col) & 1ull) ? 1.0f : 0.0f;
          out[xbase + (long)(c0 + r) * Tn + t0p + col] = v; // fire & forget
        }
      }
      wg_barrier();
    }
    {                                          // epilogue: chunk 15
      const int t0p = (NCH - 1) * TT;
#pragma unroll 8
      for (int r = 0; r < CB; ++r) {
        const unsigned long long wb = Sb[(NCH - 1) & 1][r];
        const float v = ((wb >> col) & 1ull) ? 1.0f : 0.0f;
        out[xbase + (long)(c0 + r) * Tn + t0p + col] = v;
      }
    }
  }
}

extern "C" void kernel_launch(void* const* d_in, const int* in_sizes, int n_in,
                              void* d_out, int out_size, void* d_ws, size_t ws_size,
                              hipStream_t stream) {
  const float* x  = (const float*)d_in[0];
  const float* w  = (const float*)d_in[1];
  float* out      = (float*)d_out;
  dim3 grid(Cn / CB, Bn, 1);
  snn_fused<<<grid, 384, 0, stream>>>(x, w, out);
}